// Round 14
// baseline (321.559 us; speedup 1.0000x reference)
//
#include <hip/hip_runtime.h>
#include <stdint.h>

typedef __attribute__((ext_vector_type(8))) short bf16x8;
typedef __attribute__((ext_vector_type(16))) float f32x16;

#define GM 8192
#define GN 4096
#define GK 4096
#define KTILES (GK / 64)

__device__ __forceinline__ unsigned short f2bf(float f) {
  union { float f; unsigned int u; } c; c.f = f;
  unsigned int u = c.u;
  unsigned int r = u + 0x7FFFu + ((u >> 16) & 1u);   // round-to-nearest-even
  return (unsigned short)(r >> 16);
}

// ---------------- x (f32) -> bf16, 8 elems/thread ----------------
__global__ __launch_bounds__(256) void cvt_x_kernel(const float* __restrict__ x,
                                                    unsigned short* __restrict__ xb) {
  int i = blockIdx.x * 256 + threadIdx.x;
  const float4* p = (const float4*)x + (size_t)i * 2;
  float4 a = p[0], b = p[1];
  unsigned short t[8] = { f2bf(a.x), f2bf(a.y), f2bf(a.z), f2bf(a.w),
                          f2bf(b.x), f2bf(b.y), f2bf(b.z), f2bf(b.w) };
  int4 pk; __builtin_memcpy(&pk, t, 16);
  ((int4*)xb)[i] = pk;
}

// -------- W_eff = weight + 2 * lora_B @ lora_A -> bf16 --------
__global__ __launch_bounds__(256) void weff_kernel(const float* __restrict__ w,
                                                   const float* __restrict__ lA,
                                                   const float* __restrict__ lB,
                                                   unsigned short* __restrict__ wb) {
  const int K = GK;
  int idx = blockIdx.x * 256 + threadIdx.x;   // over (N/8)*(K/8) = 512*512
  int cg = idx & 511;
  int rg = idx >> 9;
  int i0 = cg << 3;
  int o0 = rg << 3;

  float acc[8][8];
#pragma unroll
  for (int r = 0; r < 8; ++r)
#pragma unroll
    for (int c = 0; c < 8; ++c) acc[r][c] = 0.f;

#pragma unroll
  for (int r = 0; r < 16; ++r) {
    float4 a0 = *(const float4*)(lA + (size_t)r * K + i0);
    float4 a1 = *(const float4*)(lA + (size_t)r * K + i0 + 4);
    float av[8] = { a0.x, a0.y, a0.z, a0.w, a1.x, a1.y, a1.z, a1.w };
#pragma unroll
    for (int row = 0; row < 8; ++row) {
      float b = lB[(size_t)(o0 + row) * 16 + r];
#pragma unroll
      for (int c = 0; c < 8; ++c) acc[row][c] += b * av[c];
    }
  }

#pragma unroll
  for (int row = 0; row < 8; ++row) {
    float4 w0 = *(const float4*)(w + (size_t)(o0 + row) * K + i0);
    float4 w1 = *(const float4*)(w + (size_t)(o0 + row) * K + i0 + 4);
    unsigned short t[8] = {
      f2bf(w0.x + 2.0f * acc[row][0]), f2bf(w0.y + 2.0f * acc[row][1]),
      f2bf(w0.z + 2.0f * acc[row][2]), f2bf(w0.w + 2.0f * acc[row][3]),
      f2bf(w1.x + 2.0f * acc[row][4]), f2bf(w1.y + 2.0f * acc[row][5]),
      f2bf(w1.z + 2.0f * acc[row][6]), f2bf(w1.w + 2.0f * acc[row][7]) };
    int4 pk; __builtin_memcpy(&pk, t, 16);
    *(int4*)(wb + (size_t)(o0 + row) * K + i0) = pk;
  }
}

// ====== 256x256 dbuf bf16 GEMM, 32x32x16 MFMA, 4 uniform K=16 phases: C = A * B^T ======
// 8 waves (2M x 4N), 128x64 C per wave (acc = 4x2 f32x16). BK=64, LDS 2 x 64 KB.
// 16x32-bf16 subtiles (1 KB), st_16x32 swizzle (pre-swizzled global src, 0 conflicts).
// Phase PH (= K-step PH*16): {stage 2 gloads; 6 ds_read (4 A + 2 B frags, sc=PH>>1);
// [P3: vmcnt(2)]; ONE barrier; setprio(1) 8 independent MFMA setprio(0)}.
// MFMA after the single barrier -> waves skew a full phase -> reads overlap MFMA.
// Stage map (2 gloads each): P0: B-sc0(kt+1)->NXT, P1: A-sc1(kt+1)->NXT,
// P2: B-sc1(kt+1)->NXT, P3: A-sc0(kt+2)->CUR + vmcnt(2) [retires tile kt+1, keeps 2].
// WAR ledger: every half's rewrite is >= 2 barriers after its last read's retirement
// (read retires at its wave's lgkm before that phase's MFMA, hence before the wave
// ARRIVES at the next barrier; writer issues only after PASSING that barrier).

__device__ __forceinline__ void gload16(const unsigned short* g, char* l) {
  __builtin_amdgcn_global_load_lds((__attribute__((address_space(1))) void*)g,
                                   (__attribute__((address_space(3))) void*)l, 16, 0, 0);
}

__device__ __forceinline__ void bar() {
  asm volatile("" ::: "memory");
  __builtin_amdgcn_s_barrier();
  asm volatile("" ::: "memory");
}

template <int N>
__device__ __forceinline__ void vmwait() {
  if constexpr (N == 0)      asm volatile("s_waitcnt vmcnt(0)" ::: "memory");
  else if constexpr (N == 2) asm volatile("s_waitcnt vmcnt(2)" ::: "memory");
}

#define MFMA32(a, b, c) __builtin_amdgcn_mfma_f32_32x32x16_bf16((a), (b), (c), 0, 0, 0)

// stage one sc-half (16 subtiles of 1 KB): wave w stages sr {2w, 2w+1}.
// ISB: 0 = A area, 1 = B area. SC: k-column half. BUF: LDS buffer.
template <int ISB, int SC, int BUF>
__device__ __forceinline__ void stage_half(const unsigned short* A, const unsigned short* B,
                                           char* smem, int bm0, int bn0, int w, int lane,
                                           int kt) {
  const unsigned short* mat = ISB ? B : A;
  const int mbase = ISB ? bn0 : bm0;
  const int gcol = ((lane & 3) * 8) ^ ((lane & 32) ? 16 : 0);   // pre-swizzled source col
#pragma unroll
  for (int i = 0; i < 2; ++i) {
    const int sr = 2 * w + i;
    const unsigned short* src = mat + (size_t)(mbase + sr * 16 + (lane >> 2)) * GK
                                    + kt * 64 + SC * 32 + gcol;
    char* dst = smem + BUF * 65536 + ISB * 32768 + ((sr * 2 + SC) << 10);
    gload16(src, dst);
  }
}

// fragment read: subtile (srPair + sub2, SC), swizzled byte (rlo*64 + kin) ^ m32
__device__ __forceinline__ bf16x8 ldsFrag(const char* smem, int byteOff) {
  return *(const bf16x8*)(smem + byteOff);
}

// TAIL: 0 steady, 1 = kt==KTILES-2 (P3: no stage, vmcnt(0)), 2 = last tile (no stage/wait)
template <int CUR, int TAIL>
__device__ __forceinline__ void ktile(const unsigned short* __restrict__ A,
                                      const unsigned short* __restrict__ B,
                                      char* smem, int bm0, int bn0, int w, int lane,
                                      int wm, int wn, int kt,
                                      f32x16 (&acc)[4][2]) {
  constexpr int NXT = CUR ^ 1;
  const int rlo = lane & 15, sub2 = (lane >> 4) & 1, khalf = lane >> 5;
  const int m32 = (rlo & 8) << 2;                      // XOR mask (bit5) for bit9=row bit3

  bf16x8 av[4], bv[2];

#define READ_PHASE(PH, BUF)                                                            \
  {                                                                                    \
    constexpr int SC = (PH) >> 1;                                                      \
    const int kin = ((PH) & 1) * 32 + khalf * 16;                                      \
    const int roff = (rlo * 64 + kin) ^ m32;                                           \
    _Pragma("unroll")                                                                  \
    for (int mi = 0; mi < 4; ++mi)                                                     \
      av[mi] = ldsFrag(smem, (BUF) * 65536 +                                           \
                       (((wm * 8 + mi * 2 + sub2) * 2 + SC) << 10) + roff);            \
    _Pragma("unroll")                                                                  \
    for (int ni = 0; ni < 2; ++ni)                                                     \
      bv[ni] = ldsFrag(smem, (BUF) * 65536 + 32768 +                                   \
                       (((wn * 4 + ni * 2 + sub2) * 2 + SC) << 10) + roff);            \
  }

#define MFMA_PHASE()                                                                   \
  __builtin_amdgcn_s_setprio(1);                                                       \
  _Pragma("unroll")                                                                    \
  for (int mi = 0; mi < 4; ++mi) {                                                     \
    acc[mi][0] = MFMA32(av[mi], bv[0], acc[mi][0]);                                    \
    acc[mi][1] = MFMA32(av[mi], bv[1], acc[mi][1]);                                    \
  }                                                                                    \
  __builtin_amdgcn_s_setprio(0);

  // ---- P0: stage B-sc0(kt+1) -> NXT ----
  if constexpr (TAIL < 2) stage_half<1, 0, NXT>(A, B, smem, bm0, bn0, w, lane, kt + 1);
  READ_PHASE(0, CUR);
  bar();
  MFMA_PHASE();

  // ---- P1: stage A-sc1(kt+1) -> NXT ----
  if constexpr (TAIL < 2) stage_half<0, 1, NXT>(A, B, smem, bm0, bn0, w, lane, kt + 1);
  READ_PHASE(1, CUR);
  bar();
  MFMA_PHASE();

  // ---- P2: stage B-sc1(kt+1) -> NXT ----
  if constexpr (TAIL < 2) stage_half<1, 1, NXT>(A, B, smem, bm0, bn0, w, lane, kt + 1);
  READ_PHASE(2, CUR);
  bar();
  MFMA_PHASE();

  // ---- P3: stage A-sc0(kt+2) -> CUR; per-tile vmcnt publishes tile kt+1 ----
  if constexpr (TAIL == 0) stage_half<0, 0, CUR>(A, B, smem, bm0, bn0, w, lane, kt + 2);
  READ_PHASE(3, CUR);
  if constexpr (TAIL == 0)      vmwait<2>();   // retire tile kt+1's 8; keep A-sc0(kt+2)
  else if constexpr (TAIL == 1) vmwait<0>();   // publish final tile
  bar();
  MFMA_PHASE();

#undef READ_PHASE
#undef MFMA_PHASE
}

__global__ __launch_bounds__(512, 2) void gemm_bt_kernel(const unsigned short* __restrict__ A,
                                                         const unsigned short* __restrict__ B,
                                                         float* __restrict__ C) {
  __shared__ alignas(16) char smem[131072];   // 2 x 64 KB

  const int t = threadIdx.x, lane = t & 63, w = t >> 6;
  const int wm = w >> 2, wn = w & 3;     // 2 x 4 wave grid, 128x64 per wave

  // bijective XCD-chunked swizzle: 512 blocks, 512 % 8 == 0
  const int bid = blockIdx.x;
  const int wg  = (bid & 7) * (512 / 8) + (bid >> 3);
  const int bx = wg & 15, by = wg >> 4;
  const int bm0 = by * 256, bn0 = bx * 256;

  // prologue: tile 0 (all 4 sc-halves) + A-sc0 of tile 1 = 10 loads/wave;
  // vmcnt(2) retires tile 0, keeps A-sc0(1) in flight; barrier publishes tile 0.
  stage_half<0, 0, 0>(A, B, smem, bm0, bn0, w, lane, 0);
  stage_half<1, 0, 0>(A, B, smem, bm0, bn0, w, lane, 0);
  stage_half<0, 1, 0>(A, B, smem, bm0, bn0, w, lane, 0);
  stage_half<1, 1, 0>(A, B, smem, bm0, bn0, w, lane, 0);
  stage_half<0, 0, 1>(A, B, smem, bm0, bn0, w, lane, 1);
  vmwait<2>();
  bar();

  f32x16 acc[4][2] = {};

  // KTILES = 64: steady tiles 0..61, tail 62 (TAIL1), 63 (TAIL2)
  for (int kt = 0; kt < KTILES - 2; kt += 2) {
    ktile<0, 0>(A, B, smem, bm0, bn0, w, lane, wm, wn, kt,     acc);
    ktile<1, 0>(A, B, smem, bm0, bn0, w, lane, wm, wn, kt + 1, acc);
  }
  ktile<0, 1>(A, B, smem, bm0, bn0, w, lane, wm, wn, KTILES - 2, acc);
  ktile<1, 2>(A, B, smem, bm0, bn0, w, lane, wm, wn, KTILES - 1, acc);

  // epilogue: 32x32 C/D layout: col = lane&31, row = (reg&3) + 8*(reg>>2) + 4*(lane>>5)
  const int ocol = lane & 31;
  const int radd = (lane >> 5) << 2;
#pragma unroll
  for (int mi = 0; mi < 4; ++mi) {
#pragma unroll
    for (int ni = 0; ni < 2; ++ni) {
      float* cp = C + (size_t)(bm0 + wm * 128 + mi * 32 + radd) * GN
                    + (bn0 + wn * 64 + ni * 32 + ocol);
#pragma unroll
      for (int r = 0; r < 16; ++r) {
        const int row = (r & 3) + 8 * (r >> 2);
        cp[(size_t)row * GN] = acc[mi][ni][r];
      }
    }
  }
}

extern "C" void kernel_launch(void* const* d_in, const int* in_sizes, int n_in,
                              void* d_out, int out_size, void* d_ws, size_t ws_size,
                              hipStream_t stream) {
  const float* x  = (const float*)d_in[0];   // [4,2048,4096] f32
  const float* w  = (const float*)d_in[1];   // [4096,4096]   f32
  const float* lA = (const float*)d_in[2];   // [16,4096]     f32
  const float* lB = (const float*)d_in[3];   // [4096,16]     f32
  float* out = (float*)d_out;                // [4,2048,4096] f32

  const int M = GM, N = GN, K = GK;

  unsigned short* xb = (unsigned short*)d_ws;          // M*K bf16 = 64MB
  unsigned short* wb = xb + (size_t)M * K;             // N*K bf16 = 32MB

  cvt_x_kernel<<<dim3((M * K / 8) / 256), dim3(256), 0, stream>>>(x, xb);
  weff_kernel<<<dim3((N / 8) * (K / 8) / 256), dim3(256), 0, stream>>>(w, lA, lB, wb);
  gemm_bt_kernel<<<dim3((M / 256) * (N / 256)), dim3(512), 0, stream>>>(xb, wb, out);
}

// Round 15
// 313.155 us; speedup vs baseline: 1.0268x; 1.0268x over previous
//
#include <hip/hip_runtime.h>
#include <stdint.h>

typedef __attribute__((ext_vector_type(8))) short bf16x8;
typedef __attribute__((ext_vector_type(16))) float f32x16;

#define GM 8192
#define GN 4096
#define GK 4096
#define KTILES (GK / 64)

__device__ __forceinline__ unsigned short f2bf(float f) {
  union { float f; unsigned int u; } c; c.f = f;
  unsigned int u = c.u;
  unsigned int r = u + 0x7FFFu + ((u >> 16) & 1u);   // round-to-nearest-even
  return (unsigned short)(r >> 16);
}

// ---------------- x (f32) -> bf16, 8 elems/thread ----------------
__global__ __launch_bounds__(256) void cvt_x_kernel(const float* __restrict__ x,
                                                    unsigned short* __restrict__ xb) {
  int i = blockIdx.x * 256 + threadIdx.x;
  const float4* p = (const float4*)x + (size_t)i * 2;
  float4 a = p[0], b = p[1];
  unsigned short t[8] = { f2bf(a.x), f2bf(a.y), f2bf(a.z), f2bf(a.w),
                          f2bf(b.x), f2bf(b.y), f2bf(b.z), f2bf(b.w) };
  int4 pk; __builtin_memcpy(&pk, t, 16);
  ((int4*)xb)[i] = pk;
}

// -------- W_eff = weight + 2 * lora_B @ lora_A -> bf16 --------
__global__ __launch_bounds__(256) void weff_kernel(const float* __restrict__ w,
                                                   const float* __restrict__ lA,
                                                   const float* __restrict__ lB,
                                                   unsigned short* __restrict__ wb) {
  const int K = GK;
  int idx = blockIdx.x * 256 + threadIdx.x;   // over (N/8)*(K/8) = 512*512
  int cg = idx & 511;
  int rg = idx >> 9;
  int i0 = cg << 3;
  int o0 = rg << 3;

  float acc[8][8];
#pragma unroll
  for (int r = 0; r < 8; ++r)
#pragma unroll
    for (int c = 0; c < 8; ++c) acc[r][c] = 0.f;

#pragma unroll
  for (int r = 0; r < 16; ++r) {
    float4 a0 = *(const float4*)(lA + (size_t)r * K + i0);
    float4 a1 = *(const float4*)(lA + (size_t)r * K + i0 + 4);
    float av[8] = { a0.x, a0.y, a0.z, a0.w, a1.x, a1.y, a1.z, a1.w };
#pragma unroll
    for (int row = 0; row < 8; ++row) {
      float b = lB[(size_t)(o0 + row) * 16 + r];
#pragma unroll
      for (int c = 0; c < 8; ++c) acc[row][c] += b * av[c];
    }
  }

#pragma unroll
  for (int row = 0; row < 8; ++row) {
    float4 w0 = *(const float4*)(w + (size_t)(o0 + row) * K + i0);
    float4 w1 = *(const float4*)(w + (size_t)(o0 + row) * K + i0 + 4);
    unsigned short t[8] = {
      f2bf(w0.x + 2.0f * acc[row][0]), f2bf(w0.y + 2.0f * acc[row][1]),
      f2bf(w0.z + 2.0f * acc[row][2]), f2bf(w0.w + 2.0f * acc[row][3]),
      f2bf(w1.x + 2.0f * acc[row][4]), f2bf(w1.y + 2.0f * acc[row][5]),
      f2bf(w1.z + 2.0f * acc[row][6]), f2bf(w1.w + 2.0f * acc[row][7]) };
    int4 pk; __builtin_memcpy(&pk, t, 16);
    *(int4*)(wb + (size_t)(o0 + row) * K + i0) = pk;
  }
}

// ====== 256x256 dbuf bf16 GEMM, 32x32x16 MFMA, 4 uniform K=16 phases: C = A * B^T ======
// 8 waves (2M x 4N), 128x64 C per wave (acc = 4x2 f32x16). BK=64, LDS 2 x 64 KB.
// 16x32-bf16 subtiles (1 KB). Swizzle = st_16x32 (byte bit5 ^= row bit3) PLUS odd-sr
// sub-swizzle (byte bit4 ^= sr bit0), applied on BOTH sides (pre-swizzled global source,
// XORed read offset). The odd-sr term kills the 32x32-fragment conflict where lanes 0-15
// (sub2=0) and 16-31 (sub2=1) read identical in-subtile offsets of bank-aligned subtiles:
// with it, the 64-lane bank map is 8 disjoint 4-bank groups x 8 lanes = 2 lanes/bank (free).
// Phase PH (= K-step PH*16): {stage 2 gloads; 6 ds_read; [P3: vmcnt(2)]; ONE barrier;
// setprio(1) 8 independent MFMA setprio(0)}. Stage map: P0 B-sc0(kt+1), P1 A-sc1(kt+1),
// P2 B-sc1(kt+1), P3 A-sc0(kt+2)+vmcnt(2) [retires tile kt+1, keeps 2 in flight].

__device__ __forceinline__ void gload16(const unsigned short* g, char* l) {
  __builtin_amdgcn_global_load_lds((__attribute__((address_space(1))) void*)g,
                                   (__attribute__((address_space(3))) void*)l, 16, 0, 0);
}

__device__ __forceinline__ void bar() {
  asm volatile("" ::: "memory");
  __builtin_amdgcn_s_barrier();
  asm volatile("" ::: "memory");
}

template <int N>
__device__ __forceinline__ void vmwait() {
  if constexpr (N == 0)      asm volatile("s_waitcnt vmcnt(0)" ::: "memory");
  else if constexpr (N == 2) asm volatile("s_waitcnt vmcnt(2)" ::: "memory");
}

#define MFMA32(a, b, c) __builtin_amdgcn_mfma_f32_32x32x16_bf16((a), (b), (c), 0, 0, 0)

// stage one sc-half (16 subtiles of 1 KB): wave w stages sr {2w, 2w+1}.
// ISB: 0 = A area, 1 = B area. SC: k-column half. BUF: LDS buffer.
// odd-sr sub-swizzle: global col ^ 8 elements (byte bit4) for sr&1.
template <int ISB, int SC, int BUF>
__device__ __forceinline__ void stage_half(const unsigned short* A, const unsigned short* B,
                                           char* smem, int bm0, int bn0, int w, int lane,
                                           int kt) {
  const unsigned short* mat = ISB ? B : A;
  const int mbase = ISB ? bn0 : bm0;
  const int gcolBase = ((lane & 3) * 8) ^ ((lane & 32) ? 16 : 0);   // st_16x32 pre-swizzle
#pragma unroll
  for (int i = 0; i < 2; ++i) {
    const int sr = 2 * w + i;
    const int gcol = gcolBase ^ (i ? 8 : 0);                        // odd-sr sub-swizzle
    const unsigned short* src = mat + (size_t)(mbase + sr * 16 + (lane >> 2)) * GK
                                    + kt * 64 + SC * 32 + gcol;
    char* dst = smem + BUF * 65536 + ISB * 32768 + ((sr * 2 + SC) << 10);
    gload16(src, dst);
  }
}

__device__ __forceinline__ bf16x8 ldsFrag(const char* smem, int byteOff) {
  return *(const bf16x8*)(smem + byteOff);
}

// TAIL: 0 steady, 1 = kt==KTILES-2 (P3: no stage, vmcnt(0)), 2 = last tile (no stage/wait)
template <int CUR, int TAIL>
__device__ __forceinline__ void ktile(const unsigned short* __restrict__ A,
                                      const unsigned short* __restrict__ B,
                                      char* smem, int bm0, int bn0, int w, int lane,
                                      int wm, int wn, int kt,
                                      f32x16 (&acc)[4][2]) {
  constexpr int NXT = CUR ^ 1;
  const int rlo = lane & 15, sub2 = (lane >> 4) & 1, khalf = lane >> 5;
  const int m32 = (rlo & 8) << 2;                      // st_16x32: byte bit5 ^= row bit3
  const int m16 = sub2 << 4;                           // odd-sr:   byte bit4 ^= sr bit0

  bf16x8 av[4], bv[2];

#define READ_PHASE(PH, BUF)                                                            \
  {                                                                                    \
    constexpr int SC = (PH) >> 1;                                                      \
    const int kin = ((PH) & 1) * 32 + khalf * 16;                                      \
    const int roff = ((rlo * 64 + kin) ^ m32) ^ m16;                                   \
    _Pragma("unroll")                                                                  \
    for (int mi = 0; mi < 4; ++mi)                                                     \
      av[mi] = ldsFrag(smem, (BUF) * 65536 +                                           \
                       (((wm * 8 + mi * 2 + sub2) * 2 + SC) << 10) + roff);            \
    _Pragma("unroll")                                                                  \
    for (int ni = 0; ni < 2; ++ni)                                                     \
      bv[ni] = ldsFrag(smem, (BUF) * 65536 + 32768 +                                   \
                       (((wn * 4 + ni * 2 + sub2) * 2 + SC) << 10) + roff);            \
  }

#define MFMA_PHASE()                                                                   \
  __builtin_amdgcn_s_setprio(1);                                                       \
  _Pragma("unroll")                                                                    \
  for (int mi = 0; mi < 4; ++mi) {                                                     \
    acc[mi][0] = MFMA32(av[mi], bv[0], acc[mi][0]);                                    \
    acc[mi][1] = MFMA32(av[mi], bv[1], acc[mi][1]);                                    \
  }                                                                                    \
  __builtin_amdgcn_s_setprio(0);

  // ---- P0: stage B-sc0(kt+1) -> NXT ----
  if constexpr (TAIL < 2) stage_half<1, 0, NXT>(A, B, smem, bm0, bn0, w, lane, kt + 1);
  READ_PHASE(0, CUR);
  bar();
  MFMA_PHASE();

  // ---- P1: stage A-sc1(kt+1) -> NXT ----
  if constexpr (TAIL < 2) stage_half<0, 1, NXT>(A, B, smem, bm0, bn0, w, lane, kt + 1);
  READ_PHASE(1, CUR);
  bar();
  MFMA_PHASE();

  // ---- P2: stage B-sc1(kt+1) -> NXT ----
  if constexpr (TAIL < 2) stage_half<1, 1, NXT>(A, B, smem, bm0, bn0, w, lane, kt + 1);
  READ_PHASE(2, CUR);
  bar();
  MFMA_PHASE();

  // ---- P3: stage A-sc0(kt+2) -> CUR; per-tile vmcnt publishes tile kt+1 ----
  if constexpr (TAIL == 0) stage_half<0, 0, CUR>(A, B, smem, bm0, bn0, w, lane, kt + 2);
  READ_PHASE(3, CUR);
  if constexpr (TAIL == 0)      vmwait<2>();   // retire tile kt+1's 8; keep A-sc0(kt+2)
  else if constexpr (TAIL == 1) vmwait<0>();   // publish final tile
  bar();
  MFMA_PHASE();

#undef READ_PHASE
#undef MFMA_PHASE
}

__global__ __launch_bounds__(512, 2) void gemm_bt_kernel(const unsigned short* __restrict__ A,
                                                         const unsigned short* __restrict__ B,
                                                         float* __restrict__ C) {
  __shared__ alignas(16) char smem[131072];   // 2 x 64 KB

  const int t = threadIdx.x, lane = t & 63, w = t >> 6;
  const int wm = w >> 2, wn = w & 3;     // 2 x 4 wave grid, 128x64 per wave

  // bijective XCD-chunked swizzle: 512 blocks, 512 % 8 == 0
  const int bid = blockIdx.x;
  const int wg  = (bid & 7) * (512 / 8) + (bid >> 3);
  const int bx = wg & 15, by = wg >> 4;
  const int bm0 = by * 256, bn0 = bx * 256;

  // prologue: tile 0 (all 4 sc-halves) + A-sc0 of tile 1 = 10 loads/wave;
  // vmcnt(2) retires tile 0, keeps A-sc0(1) in flight; barrier publishes tile 0.
  stage_half<0, 0, 0>(A, B, smem, bm0, bn0, w, lane, 0);
  stage_half<1, 0, 0>(A, B, smem, bm0, bn0, w, lane, 0);
  stage_half<0, 1, 0>(A, B, smem, bm0, bn0, w, lane, 0);
  stage_half<1, 1, 0>(A, B, smem, bm0, bn0, w, lane, 0);
  stage_half<0, 0, 1>(A, B, smem, bm0, bn0, w, lane, 1);
  vmwait<2>();
  bar();

  f32x16 acc[4][2] = {};

  // KTILES = 64: steady tiles 0..61, tail 62 (TAIL1), 63 (TAIL2)
  for (int kt = 0; kt < KTILES - 2; kt += 2) {
    ktile<0, 0>(A, B, smem, bm0, bn0, w, lane, wm, wn, kt,     acc);
    ktile<1, 0>(A, B, smem, bm0, bn0, w, lane, wm, wn, kt + 1, acc);
  }
  ktile<0, 1>(A, B, smem, bm0, bn0, w, lane, wm, wn, KTILES - 2, acc);
  ktile<1, 2>(A, B, smem, bm0, bn0, w, lane, wm, wn, KTILES - 1, acc);

  // epilogue: 32x32 C/D layout: col = lane&31, row = (reg&3) + 8*(reg>>2) + 4*(lane>>5)
  const int ocol = lane & 31;
  const int radd = (lane >> 5) << 2;
#pragma unroll
  for (int mi = 0; mi < 4; ++mi) {
#pragma unroll
    for (int ni = 0; ni < 2; ++ni) {
      float* cp = C + (size_t)(bm0 + wm * 128 + mi * 32 + radd) * GN
                    + (bn0 + wn * 64 + ni * 32 + ocol);
#pragma unroll
      for (int r = 0; r < 16; ++r) {
        const int row = (r & 3) + 8 * (r >> 2);
        cp[(size_t)row * GN] = acc[mi][ni][r];
      }
    }
  }
}

extern "C" void kernel_launch(void* const* d_in, const int* in_sizes, int n_in,
                              void* d_out, int out_size, void* d_ws, size_t ws_size,
                              hipStream_t stream) {
  const float* x  = (const float*)d_in[0];   // [4,2048,4096] f32
  const float* w  = (const float*)d_in[1];   // [4096,4096]   f32
  const float* lA = (const float*)d_in[2];   // [16,4096]     f32
  const float* lB = (const float*)d_in[3];   // [4096,16]     f32
  float* out = (float*)d_out;                // [4,2048,4096] f32

  const int M = GM, N = GN, K = GK;

  unsigned short* xb = (unsigned short*)d_ws;          // M*K bf16 = 64MB
  unsigned short* wb = xb + (size_t)M * K;             // N*K bf16 = 32MB

  cvt_x_kernel<<<dim3((M * K / 8) / 256), dim3(256), 0, stream>>>(x, xb);
  weff_kernel<<<dim3((N / 8) * (K / 8) / 256), dim3(256), 0, stream>>>(w, lA, lB, wb);
  gemm_bt_kernel<<<dim3((M / 256) * (N / 256)), dim3(512), 0, stream>>>(xb, wb, out);
}